// Round 5
// baseline (439.037 us; speedup 1.0000x reference)
//
#include <hip/hip_runtime.h>

#define Bn 64
#define Tn 512
#define En 2048
#define Kn 32
#define Mn (Bn*Tn)          // 32768 rows
#define LOG2E 1.4426950408889634f
#define LN2   0.6931471805599453f
#define NSEG 8
#define SEGLEN 64

typedef __attribute__((ext_vector_type(8)))  short short8;
typedef __attribute__((ext_vector_type(4)))  float floatx4;
typedef __attribute__((ext_vector_type(16))) float floatx16;

__device__ inline unsigned int pack_bf16(float a, float b) {
    unsigned int ua = __float_as_uint(a), ub = __float_as_uint(b);
    return ((ua + 0x8000u) >> 16) | (((ub + 0x8000u) & 0xFFFF0000u));
}
__device__ inline unsigned int pack_trunc(float lo, float hi) {
    return (__float_as_uint(lo) >> 16) | (__float_as_uint(hi) & 0xFFFF0000u);
}
__device__ inline float rdlane(float v, int l) {
    return __uint_as_float(__builtin_amdgcn_readlane(__float_as_uint(v), l));
}

// ---------------- prep: W (fp32 [E][K]) -> Wt (bf16 [K][E]), zero out ----------------
__global__ __launch_bounds__(256) void prep_kernel(const float* __restrict__ W,
                                                   unsigned short* __restrict__ Wt,
                                                   float* __restrict__ out) {
    int idx = blockIdx.x * 256 + threadIdx.x;      // 65536 total
    int k = idx >> 11, e = idx & 2047;
    float w = W[e * Kn + k];
    Wt[idx] = (unsigned short)((__float_as_uint(w) + 0x8000u) >> 16);
    if (idx == 0) out[0] = 0.f;
}

__device__ inline int seq_len(const void* maskp, int b, int lane) {
    unsigned int first = *(const unsigned int*)maskp;
    int mode = (first <= 1u) ? 0 : (first == 0x3F800000u ? 2 : 1);
    int len = 0;
    if (mode == 0) {
        const int* mb = (const int*)maskp + b * Tn;
        for (int t = lane; t < Tn; t += 64) len += (mb[t] != 0);
    } else if (mode == 1) {
        const unsigned char* mb = (const unsigned char*)maskp + b * Tn;
        for (int t = lane; t < Tn; t += 64) len += (mb[t] != 0);
    } else {
        const float* mb = (const float*)maskp + b * Tn;
        for (int t = lane; t < Tn; t += 64) len += (mb[t] != 0.f);
    }
    #pragma unroll
    for (int o = 32; o; o >>= 1) len += __shfl_xor(len, o, 64);
    return len;
}

// ---------------- fused GEMM + segment transfer-product ----------------
// Block i: rows [64i, 64i+64) == (batch i>>3, segment i&7).
// Phase 1 (4 waves): barrier-free streaming MFMA gemm -> global logits2 + LDS.
// Phase 2 (wave 0): H_s = (M_a..M_b)^T via 2x mfma_32x32x16_bf16 per step,
//   emissions from LDS. A-layout row m = lane&31 -> per-lane e[j] row scale;
//   C layout col = lane&31, row = (r&3)+8*(r>>2)+4*(lane>>5)  [m74/m101].
__global__ __launch_bounds__(256) void gemm_seg_kernel(const float* __restrict__ X,
                                                       const float* __restrict__ bias,
                                                       const unsigned short* __restrict__ Wt,
                                                       const void* __restrict__ maskp,
                                                       const float* __restrict__ trans,
                                                       float* __restrict__ logits2,
                                                       float* __restrict__ Hs,
                                                       float* __restrict__ Ss) {
    __shared__ float sL[64][33];

    const int tid  = threadIdx.x;
    const int wave = tid >> 6;
    const int lane = tid & 63;
    const int ml   = lane & 15;
    const int quad = lane >> 4;
    const int row0 = blockIdx.x * 64;

    // ---- phase 1: gemm ----
    {
        const float*          xp  = X  + (size_t)(row0 + wave * 16 + ml) * En + quad * 8;
        const unsigned short* b0p = Wt + ml * En        + quad * 8;
        const unsigned short* b1p = Wt + (16 + ml) * En + quad * 8;

        floatx4 acc0 = {0.f,0.f,0.f,0.f};
        floatx4 acc1 = {0.f,0.f,0.f,0.f};

        #pragma unroll 8
        for (int e0 = 0; e0 < En; e0 += 32) {
            float4 xa = *(const float4*)(xp + e0);
            float4 xb = *(const float4*)(xp + e0 + 4);
            short8 b0 = *(const short8*)(b0p + e0);
            short8 b1 = *(const short8*)(b1p + e0);
            union { unsigned int u[4]; short8 s; } av;
            av.u[0] = pack_bf16(xa.x, xa.y);
            av.u[1] = pack_bf16(xa.z, xa.w);
            av.u[2] = pack_bf16(xb.x, xb.y);
            av.u[3] = pack_bf16(xb.z, xb.w);
            acc0 = __builtin_amdgcn_mfma_f32_16x16x32_bf16(av.s, b0, acc0, 0, 0, 0);
            acc1 = __builtin_amdgcn_mfma_f32_16x16x32_bf16(av.s, b1, acc1, 0, 0, 0);
        }

        const float bc0 = bias[ml], bc1 = bias[16 + ml];
        const int gr = row0 + wave * 16 + quad * 4;
        const int rl = wave * 16 + quad * 4;
        #pragma unroll
        for (int r = 0; r < 4; ++r) {
            float v0 = (acc0[r] + bc0) * LOG2E;
            float v1 = (acc1[r] + bc1) * LOG2E;
            logits2[(size_t)(gr + r) * Kn + ml]      = v0;
            logits2[(size_t)(gr + r) * Kn + 16 + ml] = v1;
            sL[rl + r][ml]      = v0;
            sL[rl + r][16 + ml] = v1;
        }
    }
    __syncthreads();
    if (wave != 0) return;

    // ---- phase 2: segment transfer product (wave 0) ----
    const int b = blockIdx.x >> 3, s = blockIdx.x & 7;
    const int j = lane & 31;
    const int h = lane >> 5;

    const int len = seq_len(maskp, b, lane);
    if (s * SEGLEN >= len) return;
    const int tstart = (s == 0) ? 1 : s * SEGLEN;
    const int tend   = min(s * SEGLEN + SEGLEN - 1, len - 1);
    const int l0   = tstart - s * SEGLEN;
    const int lend = tend   - s * SEGLEN;

    float PT1[8], PT2[8];
    #pragma unroll
    for (int i = 0; i < 8; ++i) {
        PT1[i] = __builtin_exp2f(trans[(8 * h + i) * Kn + j] * LOG2E);
        PT2[i] = __builtin_exp2f(trans[(16 + 8 * h + i) * Kn + j] * LOG2E);
    }

    union U4 { unsigned int u[4]; short8 v; };
    U4 fb1, fb2;
    #pragma unroll
    for (int p = 0; p < 4; ++p) { fb1.u[p] = 0u; fb2.u[p] = 0u; }
    int i1 = j - 8 * h;
    if (i1 >= 0 && i1 < 8) fb1.u[i1 >> 1] |= 0x3F80u << (16 * (i1 & 1));
    int i2 = j - 16 - 8 * h;
    if (i2 >= 0 && i2 < 8) fb2.u[i2 >> 1] |= 0x3F80u << (16 * (i2 & 1));

    floatx16 Hc;
    float S = 0.f;
    int stepc = 0;

    float cur[4], nxt[4];
    #pragma unroll
    for (int q = 0; q < 4; ++q) cur[q] = sL[min(l0 + q, lend)][j];

    for (int g = l0; g <= lend; g += 4) {
        #pragma unroll
        for (int q = 0; q < 4; ++q) nxt[q] = sL[min(g + 4 + q, lend)][j];
        #pragma unroll
        for (int q = 0; q < 4; ++q) {
            if (g + q <= lend) {
                float e = __builtin_exp2f(cur[q]);
                U4 fa1, fa2;
                #pragma unroll
                for (int p = 0; p < 4; ++p) {
                    fa1.u[p] = pack_trunc(e * PT1[2 * p], e * PT1[2 * p + 1]);
                    fa2.u[p] = pack_trunc(e * PT2[2 * p], e * PT2[2 * p + 1]);
                }
                floatx16 acc = {0.f,0.f,0.f,0.f,0.f,0.f,0.f,0.f,
                                0.f,0.f,0.f,0.f,0.f,0.f,0.f,0.f};
                acc = __builtin_amdgcn_mfma_f32_32x32x16_bf16(fa1.v, fb1.v, acc, 0, 0, 0);
                acc = __builtin_amdgcn_mfma_f32_32x32x16_bf16(fa2.v, fb2.v, acc, 0, 0, 0);

                if ((stepc & 7) == 7) {       // renorm every 8 steps
                    float m = acc[0];
                    #pragma unroll
                    for (int r = 1; r < 16; ++r) m = fmaxf(m, acc[r]);
                    #pragma unroll
                    for (int o = 1; o < 64; o <<= 1) m = fmaxf(m, __shfl_xor(m, o, 64));
                    int eb = (int)((__float_as_uint(m) >> 23) & 0xFF);
                    float scale = __uint_as_float((unsigned int)(254 - eb) << 23);
                    #pragma unroll
                    for (int r = 0; r < 16; ++r) acc[r] *= scale;
                    S += (float)(eb - 127);
                }
                ++stepc;
                Hc = acc;

                unsigned int w[8], pw[8];
                #pragma unroll
                for (int p = 0; p < 8; ++p) w[p] = pack_trunc(acc[2 * p], acc[2 * p + 1]);
                #pragma unroll
                for (int p = 0; p < 8; ++p) pw[p] = __shfl_xor(w[p], 32, 64);
                if (h == 0) {
                    fb1.u[0] = w[0];  fb1.u[1] = w[1];  fb1.u[2] = pw[0]; fb1.u[3] = pw[1];
                    fb2.u[0] = w[4];  fb2.u[1] = w[5];  fb2.u[2] = pw[4]; fb2.u[3] = pw[5];
                } else {
                    fb1.u[0] = pw[2]; fb1.u[1] = pw[3]; fb1.u[2] = w[2];  fb1.u[3] = w[3];
                    fb2.u[0] = pw[6]; fb2.u[1] = pw[7]; fb2.u[2] = w[6];  fb2.u[3] = w[7];
                }
            }
        }
        #pragma unroll
        for (int q = 0; q < 4; ++q) cur[q] = nxt[q];
    }

    float* hp = Hs + (size_t)(b * 8 + s) * 1024;
    #pragma unroll
    for (int r = 0; r < 16; ++r) {
        int row = (r & 3) + 8 * (r >> 2) + 4 * h;
        hp[row * 32 + j] = Hc[r];
    }
    if (lane == 0) Ss[b * 8 + s] = S;
}

// ---------------- CRF phase B: per-batch combine + numerator ----------------
__global__ __launch_bounds__(64) void crf_comb_kernel(const float* __restrict__ logits2,
                                                      const int* __restrict__ y,
                                                      const void* __restrict__ maskp,
                                                      const float* __restrict__ trans,
                                                      const float* __restrict__ start,
                                                      const float* __restrict__ endt,
                                                      const float* __restrict__ Hs,
                                                      const float* __restrict__ Ss,
                                                      float* __restrict__ out) {
    const int b = blockIdx.x;
    const int lane = threadIdx.x;
    const int j = lane & 31;

    const int len = seq_len(maskp, b, lane);

    // numerator (log2 domain)
    const int* yb = y + b * Tn;
    float num2 = 0.f;
    for (int t = lane; t < Tn; t += 64) {
        if (t < len) {
            int yt = yb[t];
            num2 += logits2[((size_t)b * Tn + t) * Kn + yt];
            if (t >= 1) num2 += trans[yb[t - 1] * Kn + yt] * LOG2E;
        }
    }
    if (lane == 0) num2 += (start[yb[0]] + endt[yb[len - 1]]) * LOG2E;
    #pragma unroll
    for (int o = 32; o; o >>= 1) num2 += __shfl_xor(num2, o, 64);

    // alpha_0 linear with log2 scale S
    float a2 = start[j] * LOG2E + logits2[(size_t)b * Tn * Kn + j];
    float m0 = a2;
    #pragma unroll
    for (int o = 1; o < 64; o <<= 1) m0 = fmaxf(m0, __shfl_xor(m0, o, 64));
    float S = m0;
    float u = __builtin_exp2f(a2 - m0);

    for (int s = 0; s < NSEG; ++s) {
        if (s * SEGLEN >= len) break;
        const float* hrow = Hs + (size_t)(b * 8 + s) * 1024 + j * 32;
        float4 hr[8];
        #pragma unroll
        for (int p = 0; p < 8; ++p) hr[p] = *(const float4*)(hrow + 4 * p);
        float v0 = 0.f, v1 = 0.f, v2 = 0.f, v3 = 0.f;
        #pragma unroll
        for (int p = 0; p < 8; ++p) {
            v0 = fmaf(hr[p].x, rdlane(u, 4 * p),     v0);
            v1 = fmaf(hr[p].y, rdlane(u, 4 * p + 1), v1);
            v2 = fmaf(hr[p].z, rdlane(u, 4 * p + 2), v2);
            v3 = fmaf(hr[p].w, rdlane(u, 4 * p + 3), v3);
        }
        float v = (v0 + v1) + (v2 + v3);
        float mm = v;
        #pragma unroll
        for (int o = 1; o < 64; o <<= 1) mm = fmaxf(mm, __shfl_xor(mm, o, 64));
        int eb = (int)((__float_as_uint(mm) >> 23) & 0xFF);
        u = v * __uint_as_float((unsigned int)(254 - eb) << 23);
        S += (float)(eb - 127) + Ss[b * 8 + s];
    }

    float fv = (lane < 32) ? u * __builtin_exp2f(endt[j] * LOG2E) : 0.f;
    #pragma unroll
    for (int o = 32; o; o >>= 1) fv += __shfl_xor(fv, o, 64);
    float den2 = S + __builtin_log2f(fv);

    if (lane == 0) atomicAdd(out, (den2 - num2) * LN2);
}

extern "C" void kernel_launch(void* const* d_in, const int* in_sizes, int n_in,
                              void* d_out, int out_size, void* d_ws, size_t ws_size,
                              hipStream_t stream) {
    const float* X     = (const float*)d_in[0];
    const int*   y     = (const int*)  d_in[1];
    const void*  mask  =               d_in[2];
    const float* W     = (const float*)d_in[3];
    const float* bias  = (const float*)d_in[4];
    const float* trans = (const float*)d_in[5];
    const float* start = (const float*)d_in[6];
    const float* endt  = (const float*)d_in[7];
    float* out = (float*)d_out;

    char* ws = (char*)d_ws;
    float*          logits2 = (float*)ws;          ws += (size_t)Mn * Kn * 4;          // 4 MB
    unsigned short* Wt      = (unsigned short*)ws; ws += (size_t)Kn * En * 2;          // 128 KB
    float*          Hs      = (float*)ws;          ws += (size_t)Bn * NSEG * 1024 * 4; // 2 MB
    float*          Ss      = (float*)ws;

    prep_kernel<<<256, 256, 0, stream>>>(W, Wt, out);
    gemm_seg_kernel<<<Mn / 64, 256, 0, stream>>>(X, bias, Wt, mask, trans, logits2, Hs, Ss);
    crf_comb_kernel<<<Bn, 64, 0, stream>>>(logits2, y, mask, trans, start, endt, Hs, Ss, out);
}